// Round 9
// baseline (57.388 us; speedup 1.0000x reference)
//
#include <hip/hip_runtime.h>
#include <math.h>

#define H      4096
#define NH     32
#define NKV    8
#define HD     128
#define CACHE  2048
#define GROUPS (NH / NKV)
#define CHUNK  32                      // positions per attention block
#define NSPL   (CACHE / CHUNK)         // max splits = 64
#define KSTR   132                     // LDS row stride (floats)
#define SCALE  0.08838834764831845f    // 1/sqrt(128)

// workspace layout (floats)
#define QOFF 0                         // q_raw[4096]
#define KOFF 4096                      // k_raw[1024]
#define VOFF 5120                      // v_raw[1024]
#define POFF 6144                      // partials: [NH][NSPL]{m,l,pad,pad,acc[128]}
#define PSTRIDE 132
#define CTXOFF (POFF + NH * NSPL * PSTRIDE)   // ctx[4096]

// ---------------- QKV GEMV: wave per row, 16-deep load pipeline ----------------
__global__ __launch_bounds__(256) void qkv_gemv(
    const float* __restrict__ x,
    const float* __restrict__ qw, const float* __restrict__ kw,
    const float* __restrict__ vw, float* __restrict__ ws) {
  __shared__ float xs[H];              // 16 KB
  const int t = threadIdx.x;
  {
    const float4* xr = (const float4*)x;
    float4* xsv = (float4*)xs;
#pragma unroll
    for (int i = 0; i < 4; ++i) xsv[i * 256 + t] = xr[i * 256 + t];
  }
  __syncthreads();

  const int wave = t >> 6;
  const int lane = t & 63;
  const int row  = blockIdx.x * 4 + wave;        // 0..6143

  const float* w;
  float* outp;
  int r;
  if (row < 4096)      { w = qw; r = row;        outp = ws + QOFF; }
  else if (row < 5120) { w = kw; r = row - 4096; outp = ws + KOFF; }
  else                 { w = vw; r = row - 5120; outp = ws + VOFF; }

  const float4* wr = (const float4*)(w + (size_t)r * H);
  float4 a[16];
#pragma unroll
  for (int j = 0; j < 16; ++j) a[j] = wr[j * 64 + lane];   // 16 loads in flight

  float sum = 0.f;
#pragma unroll
  for (int j = 0; j < 16; ++j) {
    const float4 b = *(const float4*)&xs[(j * 64 + lane) * 4];
    sum = fmaf(a[j].x, b.x, sum);
    sum = fmaf(a[j].y, b.y, sum);
    sum = fmaf(a[j].z, b.z, sum);
    sum = fmaf(a[j].w, b.w, sum);
  }
#pragma unroll
  for (int off = 32; off > 0; off >>= 1) sum += __shfl_xor(sum, off);
  if (lane == 0) outp[r] = sum;
}

// ------------- attention: block = (kv head, 32-pos chunk), all 4 q-heads -------------
__global__ __launch_bounds__(256) void attn_split(
    const float* __restrict__ kcache, const float* __restrict__ vcache,
    const float* __restrict__ cosc, const float* __restrict__ sinc,
    const int* __restrict__ curp, float* __restrict__ ws) {
  const int kh    = blockIdx.x;
  const int split = blockIdx.y;
  const int cur   = curp[0];
  const int total = cur + 1;
  const int p0    = split * CHUNK;
  if (p0 >= total) return;

  __shared__ float Ks[CHUNK * KSTR];
  __shared__ float Vs[CHUNK * KSTR];
  __shared__ float q_s[GROUPS * HD];
  __shared__ float es[GROUPS][CHUNK];

  const int t = threadIdx.x;

  // ---- stage K/V chunk into LDS: batched float4 loads, 8 rows/round
  {
    const int r4 = t >> 5;            // 0..7
    const int c4 = (t & 31) * 4;      // float offset within row
    const float* kb = kcache + (size_t)kh * CACHE * HD;
    const float* vb = vcache + (size_t)kh * CACHE * HD;
#pragma unroll
    for (int rr = 0; rr < CHUNK; rr += 8) {
      const int row = rr + r4;
      const int p   = min(p0 + row, cur);      // clamp: rows past cur masked later
      if (p0 + row != cur) {                   // row 'cur' filled from fresh k/v below
        float4 kv = *(const float4*)(kb + (size_t)p * HD + c4);
        float4 vv = *(const float4*)(vb + (size_t)p * HD + c4);
        *(float4*)&Ks[row * KSTR + c4] = kv;
        *(float4*)&Vs[row * KSTR + c4] = vv;
      }
    }
  }
  // ---- RoPE q for this group's 4 heads (512 values, 2/thread)
#pragma unroll
  for (int i = 0; i < 2; ++i) {
    const int idx = t + i * 256;
    const int qh = idx >> 7, d = idx & 127;
    const int h = kh * GROUPS + qh;
    const float c  = cosc[(size_t)cur * HD + d];
    const float s  = sinc[(size_t)cur * HD + d];
    const float x1 = ws[QOFF + h * HD + d];
    const float x2 = (d < HD / 2) ? -ws[QOFF + h * HD + d + HD / 2]
                                  :  ws[QOFF + h * HD + d - HD / 2];
    q_s[qh * HD + d] = x1 * c + x2 * s;
  }
  // ---- fresh k (RoPE'd) / v into row cur-p0 if this chunk contains cur
  if (cur >= p0 && cur < p0 + CHUNK) {
    const int row = cur - p0;
    if (t < HD) {
      const int d = t;
      const float c  = cosc[(size_t)cur * HD + d];
      const float s  = sinc[(size_t)cur * HD + d];
      const float k1 = ws[KOFF + kh * HD + d];
      const float k2 = (d < HD / 2) ? -ws[KOFF + kh * HD + d + HD / 2]
                                    :  ws[KOFF + kh * HD + d - HD / 2];
      Ks[row * KSTR + d] = k1 * c + k2 * s;
    } else if (t < 2 * HD) {
      const int d = t - HD;
      Vs[row * KSTR + d] = ws[VOFF + kh * HD + d];
    }
  }
  __syncthreads();

  // ---- scores + softmax: thread t<128 owns one (qh, pos); 32-lane group = one qh
  if (t < 128) {
    const int qh = t >> 5, pos = t & 31;
    float4 a = make_float4(0.f, 0.f, 0.f, 0.f);
#pragma unroll
    for (int j = 0; j < HD / 4; ++j) {
      float4 kv = *(const float4*)&Ks[pos * KSTR + j * 4];
      float4 qv = *(const float4*)&q_s[qh * HD + j * 4];
      a.x += kv.x * qv.x; a.y += kv.y * qv.y;
      a.z += kv.z * qv.z; a.w += kv.w * qv.w;
    }
    float s = (a.x + a.y + a.z + a.w) * SCALE;
    const bool valid = (p0 + pos) < total;
    s = valid ? s : -INFINITY;
    float m = s;
#pragma unroll
    for (int off = 16; off > 0; off >>= 1) m = fmaxf(m, __shfl_xor(m, off));
    const float e = valid ? __expf(s - m) : 0.f;
    float l = e;
#pragma unroll
    for (int off = 16; off > 0; off >>= 1) l += __shfl_xor(l, off);
    es[qh][pos] = e;
    if (pos == 0) {
      float* part = ws + POFF + (size_t)((kh * GROUPS + qh) * NSPL + split) * PSTRIDE;
      part[0] = m; part[1] = l;
    }
  }
  __syncthreads();

  // ---- P.V from LDS: thread -> (qh, d-pair), unrolled 32-pos loop
  {
    const int qh = t >> 6;
    const int d0 = (t & 63) * 2;
    float2 acc = make_float2(0.f, 0.f);
#pragma unroll
    for (int pos = 0; pos < CHUNK; ++pos) {
      const float w = es[qh][pos];
      const float2 vv = *(const float2*)&Vs[pos * KSTR + d0];
      acc.x += w * vv.x; acc.y += w * vv.y;
    }
    float* part = ws + POFF + (size_t)((kh * GROUPS + qh) * NSPL + split) * PSTRIDE;
    part[4 + d0]     = acc.x;
    part[4 + d0 + 1] = acc.y;
  }
}

// ---------------- combine splits ----------------
__global__ __launch_bounds__(128) void attn_combine(
    const int* __restrict__ curp, float* __restrict__ ws) {
  const int h = blockIdx.x;
  const int t = threadIdx.x;
  const int total = curp[0] + 1;
  const int nspl = (total + CHUNK - 1) / CHUNK;
  __shared__ float wsh[64];
  __shared__ float Lsh;

  if (t < 64) {
    float mt = -INFINITY, lt = 0.f;
    if (t < nspl) {
      const float* part = ws + POFF + (size_t)(h * NSPL + t) * PSTRIDE;
      mt = part[0]; lt = part[1];
    }
    float M = mt;
#pragma unroll
    for (int off = 32; off > 0; off >>= 1) M = fmaxf(M, __shfl_xor(M, off));
    const float w = (t < nspl) ? __expf(mt - M) : 0.f;
    float lw = lt * w;
#pragma unroll
    for (int off = 32; off > 0; off >>= 1) lw += __shfl_xor(lw, off);
    wsh[t] = w;
    if (t == 0) Lsh = lw;
  }
  __syncthreads();

  const float Linv = 1.f / Lsh;
  float acc = 0.f;
#pragma unroll 8
  for (int i = 0; i < nspl; ++i)
    acc += wsh[i] * ws[POFF + (size_t)(h * NSPL + i) * PSTRIDE + 4 + t];
  ws[CTXOFF + h * HD + t] = acc * Linv;
}

// ---------------- output projection GEMV: same 16-deep pipeline ----------------
__global__ __launch_bounds__(256) void o_gemv(
    const float* __restrict__ ow, const float* __restrict__ ws,
    float* __restrict__ out) {
  __shared__ float xs[H];              // 16 KB (ctx)
  const int t = threadIdx.x;
  {
    const float4* xr = (const float4*)(ws + CTXOFF);
    float4* xsv = (float4*)xs;
#pragma unroll
    for (int i = 0; i < 4; ++i) xsv[i * 256 + t] = xr[i * 256 + t];
  }
  __syncthreads();

  const int wave = t >> 6;
  const int lane = t & 63;
  const int row  = blockIdx.x * 4 + wave;

  const float4* wr = (const float4*)(ow + (size_t)row * H);
  float4 a[16];
#pragma unroll
  for (int j = 0; j < 16; ++j) a[j] = wr[j * 64 + lane];

  float sum = 0.f;
#pragma unroll
  for (int j = 0; j < 16; ++j) {
    const float4 b = *(const float4*)&xs[(j * 64 + lane) * 4];
    sum = fmaf(a[j].x, b.x, sum);
    sum = fmaf(a[j].y, b.y, sum);
    sum = fmaf(a[j].z, b.z, sum);
    sum = fmaf(a[j].w, b.w, sum);
  }
#pragma unroll
  for (int off = 32; off > 0; off >>= 1) sum += __shfl_xor(sum, off);
  if (lane == 0) out[row] = sum;
}

extern "C" void kernel_launch(void* const* d_in, const int* in_sizes, int n_in,
                              void* d_out, int out_size, void* d_ws, size_t ws_size,
                              hipStream_t stream) {
  const float* hs   = (const float*)d_in[0];   // hidden_states (1,1,4096)
  const float* kc   = (const float*)d_in[2];   // (1,8,2048,128)
  const float* vc   = (const float*)d_in[3];
  const float* qw   = (const float*)d_in[4];   // (4096,4096)
  const float* kw   = (const float*)d_in[5];   // (1024,4096)
  const float* vw   = (const float*)d_in[6];   // (1024,4096)
  const float* ow   = (const float*)d_in[7];   // (4096,4096)
  const float* cosc = (const float*)d_in[8];   // (1,4096,128)
  const float* sinc = (const float*)d_in[9];
  const int*   cur  = (const int*)d_in[11];    // current_pos scalar
  float* ws  = (float*)d_ws;
  float* out = (float*)d_out;

  // ATTRIBUTION ROUND: qkv launched twice (idempotent — identical output).
  // dur_us - 42.65 (R2 baseline) = true in-graph cost of one qkv dispatch.
  qkv_gemv<<<1536, 256, 0, stream>>>(hs, qw, kw, vw, ws);
  qkv_gemv<<<1536, 256, 0, stream>>>(hs, qw, kw, vw, ws);
  attn_split<<<dim3(NKV, NSPL), 256, 0, stream>>>(kc, vc, cosc, sinc, cur, ws);
  attn_combine<<<NH, 128, 0, stream>>>(cur, ws);
  o_gemv<<<1024, 256, 0, stream>>>(ow, ws, out);
}

// Round 10
// 52.300 us; speedup vs baseline: 1.0973x; 1.0973x over previous
//
#include <hip/hip_runtime.h>
#include <math.h>

#define H      4096
#define NH     32
#define NKV    8
#define HD     128
#define CACHE  2048
#define GROUPS (NH / NKV)
#define CHUNK  32                      // positions per attention block
#define NSPL   (CACHE / CHUNK)         // max splits = 64
#define KSTR   132                     // LDS row stride (floats)
#define SCALE  0.08838834764831845f    // 1/sqrt(128)

// workspace layout (floats)
#define QOFF 0                         // q_raw[4096]
#define KOFF 4096                      // k_raw[1024]
#define VOFF 5120                      // v_raw[1024]
#define POFF 6144                      // partials: [NH][NSPL]{m,l,pad,pad,acc[128]}
#define PSTRIDE 132
#define CTXOFF (POFF + NH * NSPL * PSTRIDE)   // ctx[4096]
#define CNTOFF (CTXOFF + 4096)                // int counters[NKV]

// ---------------- QKV GEMV: wave per row (R2, proven 6.8 TB/s) ----------------
__global__ __launch_bounds__(256) void qkv_gemv(
    const float* __restrict__ x,
    const float* __restrict__ qw, const float* __restrict__ kw,
    const float* __restrict__ vw, float* __restrict__ ws) {
  __shared__ float xs[H];              // 16 KB
  const int t = threadIdx.x;
  if (blockIdx.x == 0 && t < NKV) ((int*)(ws + CNTOFF))[t] = 0;  // combine counters
  {
    const float4* xr = (const float4*)x;
    float4* xsv = (float4*)xs;
#pragma unroll
    for (int i = 0; i < 4; ++i) xsv[i * 256 + t] = xr[i * 256 + t];
  }
  __syncthreads();

  const int wave = t >> 6;
  const int lane = t & 63;
  const int row  = blockIdx.x * 4 + wave;        // 0..6143

  const float* w;
  float* outp;
  int r;
  if (row < 4096)      { w = qw; r = row;        outp = ws + QOFF; }
  else if (row < 5120) { w = kw; r = row - 4096; outp = ws + KOFF; }
  else                 { w = vw; r = row - 5120; outp = ws + VOFF; }

  const float4* wr = (const float4*)(w + (size_t)r * H);
  float4 a[16];
#pragma unroll
  for (int j = 0; j < 16; ++j) a[j] = wr[j * 64 + lane];

  float sum = 0.f;
#pragma unroll
  for (int j = 0; j < 16; ++j) {
    const float4 b = *(const float4*)&xs[(j * 64 + lane) * 4];
    sum = fmaf(a[j].x, b.x, sum);
    sum = fmaf(a[j].y, b.y, sum);
    sum = fmaf(a[j].z, b.z, sum);
    sum = fmaf(a[j].w, b.w, sum);
  }
#pragma unroll
  for (int off = 32; off > 0; off >>= 1) sum += __shfl_xor(sum, off);
  if (lane == 0) outp[r] = sum;
}

// ------- attention: block = (kv head, 32-pos chunk); last block per head combines -------
__global__ __launch_bounds__(256) void attn_split(
    const float* __restrict__ kcache, const float* __restrict__ vcache,
    const float* __restrict__ cosc, const float* __restrict__ sinc,
    const int* __restrict__ curp, float* __restrict__ ws) {
  const int kh    = blockIdx.x;
  const int split = blockIdx.y;
  const int cur   = curp[0];
  const int total = cur + 1;
  const int p0    = split * CHUNK;
  if (p0 >= total) return;
  const int nactive = (total + CHUNK - 1) / CHUNK;

  __shared__ float Ks[CHUNK * KSTR];
  __shared__ float Vs[CHUNK * KSTR];
  __shared__ float q_s[GROUPS * HD];
  __shared__ float es[GROUPS][CHUNK];
  __shared__ float cw[GROUPS][64];
  __shared__ float cLinv[GROUPS];
  __shared__ int   lastflag;

  const int t = threadIdx.x;

  // ---- stage K/V chunk into LDS
  {
    const int r4 = t >> 5;
    const int c4 = (t & 31) * 4;
    const float* kb = kcache + (size_t)kh * CACHE * HD;
    const float* vb = vcache + (size_t)kh * CACHE * HD;
#pragma unroll
    for (int rr = 0; rr < CHUNK; rr += 8) {
      const int row = rr + r4;
      const int p   = min(p0 + row, cur);
      if (p0 + row != cur) {
        float4 kv = *(const float4*)(kb + (size_t)p * HD + c4);
        float4 vv = *(const float4*)(vb + (size_t)p * HD + c4);
        *(float4*)&Ks[row * KSTR + c4] = kv;
        *(float4*)&Vs[row * KSTR + c4] = vv;
      }
    }
  }
  // ---- RoPE q for this group's 4 heads
#pragma unroll
  for (int i = 0; i < 2; ++i) {
    const int idx = t + i * 256;
    const int qh = idx >> 7, d = idx & 127;
    const int h = kh * GROUPS + qh;
    const float c  = cosc[(size_t)cur * HD + d];
    const float s  = sinc[(size_t)cur * HD + d];
    const float x1 = ws[QOFF + h * HD + d];
    const float x2 = (d < HD / 2) ? -ws[QOFF + h * HD + d + HD / 2]
                                  :  ws[QOFF + h * HD + d - HD / 2];
    q_s[qh * HD + d] = x1 * c + x2 * s;
  }
  // ---- fresh k (RoPE'd) / v into row cur-p0
  if (cur >= p0 && cur < p0 + CHUNK) {
    const int row = cur - p0;
    if (t < HD) {
      const int d = t;
      const float c  = cosc[(size_t)cur * HD + d];
      const float s  = sinc[(size_t)cur * HD + d];
      const float k1 = ws[KOFF + kh * HD + d];
      const float k2 = (d < HD / 2) ? -ws[KOFF + kh * HD + d + HD / 2]
                                    :  ws[KOFF + kh * HD + d - HD / 2];
      Ks[row * KSTR + d] = k1 * c + k2 * s;
    } else if (t < 2 * HD) {
      const int d = t - HD;
      Vs[row * KSTR + d] = ws[VOFF + kh * HD + d];
    }
  }
  __syncthreads();

  // ---- scores + softmax
  if (t < 128) {
    const int qh = t >> 5, pos = t & 31;
    float4 a = make_float4(0.f, 0.f, 0.f, 0.f);
#pragma unroll
    for (int j = 0; j < HD / 4; ++j) {
      float4 kv = *(const float4*)&Ks[pos * KSTR + j * 4];
      float4 qv = *(const float4*)&q_s[qh * HD + j * 4];
      a.x += kv.x * qv.x; a.y += kv.y * qv.y;
      a.z += kv.z * qv.z; a.w += kv.w * qv.w;
    }
    float s = (a.x + a.y + a.z + a.w) * SCALE;
    const bool valid = (p0 + pos) < total;
    s = valid ? s : -INFINITY;
    float m = s;
#pragma unroll
    for (int off = 16; off > 0; off >>= 1) m = fmaxf(m, __shfl_xor(m, off));
    const float e = valid ? __expf(s - m) : 0.f;
    float l = e;
#pragma unroll
    for (int off = 16; off > 0; off >>= 1) l += __shfl_xor(l, off);
    es[qh][pos] = e;
    if (pos == 0) {
      float* part = ws + POFF + (size_t)((kh * GROUPS + qh) * NSPL + split) * PSTRIDE;
      part[0] = m; part[1] = l;
    }
  }
  __syncthreads();

  // ---- P.V
  {
    const int qh = t >> 6;
    const int d0 = (t & 63) * 2;
    float2 acc = make_float2(0.f, 0.f);
#pragma unroll
    for (int pos = 0; pos < CHUNK; ++pos) {
      const float w = es[qh][pos];
      const float2 vv = *(const float2*)&Vs[pos * KSTR + d0];
      acc.x += w * vv.x; acc.y += w * vv.y;
    }
    float* part = ws + POFF + (size_t)((kh * GROUPS + qh) * NSPL + split) * PSTRIDE;
    part[4 + d0]     = acc.x;
    part[4 + d0 + 1] = acc.y;
  }

  // ---- last block for this kv-head combines all 4 heads (split-k pattern)
  if (t == 0) {
    __threadfence();                   // release partials device-wide
    int* cnt = (int*)(ws + CNTOFF);
    const int old = __hip_atomic_fetch_add(&cnt[kh], 1, __ATOMIC_ACQ_REL,
                                           __HIP_MEMORY_SCOPE_AGENT);
    lastflag = (old == nactive - 1);
  }
  __syncthreads();
  if (!lastflag) return;

  {
    const int qh   = t >> 6;
    const int lane = t & 63;
    const float* pb = ws + POFF + (size_t)((kh * GROUPS + qh) * NSPL) * PSTRIDE;
    float mt = -INFINITY, lt = 0.f;
    if (lane < nactive) { mt = pb[lane * PSTRIDE]; lt = pb[lane * PSTRIDE + 1]; }
    float M = mt;
#pragma unroll
    for (int off = 32; off > 0; off >>= 1) M = fmaxf(M, __shfl_xor(M, off));
    const float wgt = (lane < nactive) ? __expf(mt - M) : 0.f;
    float lw = lt * wgt;
#pragma unroll
    for (int off = 32; off > 0; off >>= 1) lw += __shfl_xor(lw, off);
    cw[qh][lane] = wgt;
    if (lane == 0) cLinv[qh] = 1.f / lw;
  }
  __syncthreads();
#pragma unroll
  for (int i = 0; i < 2; ++i) {
    const int idx = t + i * 256;
    const int hh  = idx >> 7;          // 0..3
    const int d   = idx & 127;
    const float* pb = ws + POFF + (size_t)((kh * GROUPS + hh) * NSPL) * PSTRIDE;
    float acc = 0.f;
    for (int s = 0; s < nactive; ++s)
      acc += cw[hh][s] * pb[s * PSTRIDE + 4 + d];
    ws[CTXOFF + (kh * GROUPS + hh) * HD + d] = acc * cLinv[hh];
  }
}

// ---------------- output projection GEMV (R2, proven) ----------------
__global__ __launch_bounds__(256) void o_gemv(
    const float* __restrict__ ow, const float* __restrict__ ws,
    float* __restrict__ out) {
  __shared__ float xs[H];              // 16 KB (ctx)
  const int t = threadIdx.x;
  {
    const float4* xr = (const float4*)(ws + CTXOFF);
    float4* xsv = (float4*)xs;
#pragma unroll
    for (int i = 0; i < 4; ++i) xsv[i * 256 + t] = xr[i * 256 + t];
  }
  __syncthreads();

  const int wave = t >> 6;
  const int lane = t & 63;
  const int row  = blockIdx.x * 4 + wave;

  const float4* wr = (const float4*)(ow + (size_t)row * H);
  float4 a[16];
#pragma unroll
  for (int j = 0; j < 16; ++j) a[j] = wr[j * 64 + lane];

  float sum = 0.f;
#pragma unroll
  for (int j = 0; j < 16; ++j) {
    const float4 b = *(const float4*)&xs[(j * 64 + lane) * 4];
    sum = fmaf(a[j].x, b.x, sum);
    sum = fmaf(a[j].y, b.y, sum);
    sum = fmaf(a[j].z, b.z, sum);
    sum = fmaf(a[j].w, b.w, sum);
  }
#pragma unroll
  for (int off = 32; off > 0; off >>= 1) sum += __shfl_xor(sum, off);
  if (lane == 0) out[row] = sum;
}

extern "C" void kernel_launch(void* const* d_in, const int* in_sizes, int n_in,
                              void* d_out, int out_size, void* d_ws, size_t ws_size,
                              hipStream_t stream) {
  const float* hs   = (const float*)d_in[0];   // hidden_states (1,1,4096)
  const float* kc   = (const float*)d_in[2];   // (1,8,2048,128)
  const float* vc   = (const float*)d_in[3];
  const float* qw   = (const float*)d_in[4];   // (4096,4096)
  const float* kw   = (const float*)d_in[5];   // (1024,4096)
  const float* vw   = (const float*)d_in[6];   // (1024,4096)
  const float* ow   = (const float*)d_in[7];   // (4096,4096)
  const float* cosc = (const float*)d_in[8];   // (1,4096,128)
  const float* sinc = (const float*)d_in[9];
  const int*   cur  = (const int*)d_in[11];    // current_pos scalar
  float* ws  = (float*)d_ws;
  float* out = (float*)d_out;

  qkv_gemv<<<1536, 256, 0, stream>>>(hs, qw, kw, vw, ws);
  attn_split<<<dim3(NKV, NSPL), 256, 0, stream>>>(kc, vc, cosc, sinc, cur, ws);
  o_gemv<<<1024, 256, 0, stream>>>(ow, ws, out);
}

// Round 11
// 49.378 us; speedup vs baseline: 1.1622x; 1.0592x over previous
//
#include <hip/hip_runtime.h>
#include <math.h>

#define H      4096
#define NH     32
#define NKV    8
#define HD     128
#define CACHE  2048
#define GROUPS (NH / NKV)
#define CHUNK  32                      // positions per attention block
#define NSPL   (CACHE / CHUNK)         // max splits = 64
#define KSTR   132                     // LDS row stride (floats)
#define SCALE  0.08838834764831845f    // 1/sqrt(128)

// workspace layout (floats)
#define QOFF 0                         // q_raw[4096]
#define KOFF 4096                      // k_raw[1024]
#define VOFF 5120                      // v_raw[1024]
#define POFF 6144                      // partials: [NH][NSPL]{m,l,pad,pad,acc[128]}
#define PSTRIDE 132
#define CTXOFF (POFF + NH * NSPL * PSTRIDE)   // ctx[4096]

// ---------------- QKV GEMV: wave per row (R2, proven) ----------------
__global__ __launch_bounds__(256) void qkv_gemv(
    const float* __restrict__ x,
    const float* __restrict__ qw, const float* __restrict__ kw,
    const float* __restrict__ vw, float* __restrict__ ws) {
  __shared__ float xs[H];              // 16 KB
  const int t = threadIdx.x;
  {
    const float4* xr = (const float4*)x;
    float4* xsv = (float4*)xs;
#pragma unroll
    for (int i = 0; i < 4; ++i) xsv[i * 256 + t] = xr[i * 256 + t];
  }
  __syncthreads();

  const int wave = t >> 6;
  const int lane = t & 63;
  const int row  = blockIdx.x * 4 + wave;        // 0..6143

  const float* w;
  float* outp;
  int r;
  if (row < 4096)      { w = qw; r = row;        outp = ws + QOFF; }
  else if (row < 5120) { w = kw; r = row - 4096; outp = ws + KOFF; }
  else                 { w = vw; r = row - 5120; outp = ws + VOFF; }

  const float4* wr = (const float4*)(w + (size_t)r * H);
  float4 a[16];
#pragma unroll
  for (int j = 0; j < 16; ++j) a[j] = wr[j * 64 + lane];   // 16 loads in flight

  float sum = 0.f;
#pragma unroll
  for (int j = 0; j < 16; ++j) {
    const float4 b = *(const float4*)&xs[(j * 64 + lane) * 4];
    sum = fmaf(a[j].x, b.x, sum);
    sum = fmaf(a[j].y, b.y, sum);
    sum = fmaf(a[j].z, b.z, sum);
    sum = fmaf(a[j].w, b.w, sum);
  }
#pragma unroll
  for (int off = 32; off > 0; off >>= 1) sum += __shfl_xor(sum, off);
  if (lane == 0) outp[r] = sum;
}

// ------------- attention: block = (kv head, 32-pos chunk), all 4 q-heads -------------
__global__ __launch_bounds__(256) void attn_split(
    const float* __restrict__ kcache, const float* __restrict__ vcache,
    const float* __restrict__ cosc, const float* __restrict__ sinc,
    const int* __restrict__ curp, float* __restrict__ ws) {
  const int kh    = blockIdx.x;
  const int split = blockIdx.y;
  const int cur   = curp[0];
  const int total = cur + 1;
  const int p0    = split * CHUNK;
  if (p0 >= total) return;

  __shared__ float Ks[CHUNK * KSTR];
  __shared__ float Vs[CHUNK * KSTR];
  __shared__ float q_s[GROUPS * HD];
  __shared__ float es[GROUPS][CHUNK];

  const int t = threadIdx.x;

  // ---- stage K/V chunk into LDS: batched float4 loads, 8 rows/round
  {
    const int r4 = t >> 5;            // 0..7
    const int c4 = (t & 31) * 4;      // float offset within row
    const float* kb = kcache + (size_t)kh * CACHE * HD;
    const float* vb = vcache + (size_t)kh * CACHE * HD;
#pragma unroll
    for (int rr = 0; rr < CHUNK; rr += 8) {
      const int row = rr + r4;
      const int p   = min(p0 + row, cur);      // clamp: rows past cur masked later
      if (p0 + row != cur) {                   // row 'cur' filled from fresh k/v below
        float4 kv = *(const float4*)(kb + (size_t)p * HD + c4);
        float4 vv = *(const float4*)(vb + (size_t)p * HD + c4);
        *(float4*)&Ks[row * KSTR + c4] = kv;
        *(float4*)&Vs[row * KSTR + c4] = vv;
      }
    }
  }
  // ---- RoPE q for this group's 4 heads (512 values, 2/thread)
#pragma unroll
  for (int i = 0; i < 2; ++i) {
    const int idx = t + i * 256;
    const int qh = idx >> 7, d = idx & 127;
    const int h = kh * GROUPS + qh;
    const float c  = cosc[(size_t)cur * HD + d];
    const float s  = sinc[(size_t)cur * HD + d];
    const float x1 = ws[QOFF + h * HD + d];
    const float x2 = (d < HD / 2) ? -ws[QOFF + h * HD + d + HD / 2]
                                  :  ws[QOFF + h * HD + d - HD / 2];
    q_s[qh * HD + d] = x1 * c + x2 * s;
  }
  // ---- fresh k (RoPE'd) / v into row cur-p0 if this chunk contains cur
  if (cur >= p0 && cur < p0 + CHUNK) {
    const int row = cur - p0;
    if (t < HD) {
      const int d = t;
      const float c  = cosc[(size_t)cur * HD + d];
      const float s  = sinc[(size_t)cur * HD + d];
      const float k1 = ws[KOFF + kh * HD + d];
      const float k2 = (d < HD / 2) ? -ws[KOFF + kh * HD + d + HD / 2]
                                    :  ws[KOFF + kh * HD + d - HD / 2];
      Ks[row * KSTR + d] = k1 * c + k2 * s;
    } else if (t < 2 * HD) {
      const int d = t - HD;
      Vs[row * KSTR + d] = ws[VOFF + kh * HD + d];
    }
  }
  __syncthreads();

  // ---- scores + softmax: thread t<128 owns one (qh, pos); 32-lane group = one qh
  if (t < 128) {
    const int qh = t >> 5, pos = t & 31;
    float4 a = make_float4(0.f, 0.f, 0.f, 0.f);
#pragma unroll
    for (int j = 0; j < HD / 4; ++j) {
      float4 kv = *(const float4*)&Ks[pos * KSTR + j * 4];
      float4 qv = *(const float4*)&q_s[qh * HD + j * 4];
      a.x += kv.x * qv.x; a.y += kv.y * qv.y;
      a.z += kv.z * qv.z; a.w += kv.w * qv.w;
    }
    float s = (a.x + a.y + a.z + a.w) * SCALE;
    const bool valid = (p0 + pos) < total;
    s = valid ? s : -INFINITY;
    float m = s;
#pragma unroll
    for (int off = 16; off > 0; off >>= 1) m = fmaxf(m, __shfl_xor(m, off));
    const float e = valid ? __expf(s - m) : 0.f;
    float l = e;
#pragma unroll
    for (int off = 16; off > 0; off >>= 1) l += __shfl_xor(l, off);
    es[qh][pos] = e;
    if (pos == 0) {
      float* part = ws + POFF + (size_t)((kh * GROUPS + qh) * NSPL + split) * PSTRIDE;
      part[0] = m; part[1] = l;
    }
  }
  __syncthreads();

  // ---- P.V from LDS: thread -> (qh, d-pair), unrolled 32-pos loop
  {
    const int qh = t >> 6;
    const int d0 = (t & 63) * 2;
    float2 acc = make_float2(0.f, 0.f);
#pragma unroll
    for (int pos = 0; pos < CHUNK; ++pos) {
      const float w = es[qh][pos];
      const float2 vv = *(const float2*)&Vs[pos * KSTR + d0];
      acc.x += w * vv.x; acc.y += w * vv.y;
    }
    float* part = ws + POFF + (size_t)((kh * GROUPS + qh) * NSPL + split) * PSTRIDE;
    part[4 + d0]     = acc.x;
    part[4 + d0 + 1] = acc.y;
  }
}

// ---------------- combine splits ----------------
__global__ __launch_bounds__(128) void attn_combine(
    const int* __restrict__ curp, float* __restrict__ ws) {
  const int h = blockIdx.x;
  const int t = threadIdx.x;
  const int total = curp[0] + 1;
  const int nspl = (total + CHUNK - 1) / CHUNK;
  __shared__ float wsh[64];
  __shared__ float Lsh;

  if (t < 64) {
    float mt = -INFINITY, lt = 0.f;
    if (t < nspl) {
      const float* part = ws + POFF + (size_t)(h * NSPL + t) * PSTRIDE;
      mt = part[0]; lt = part[1];
    }
    float M = mt;
#pragma unroll
    for (int off = 32; off > 0; off >>= 1) M = fmaxf(M, __shfl_xor(M, off));
    const float w = (t < nspl) ? __expf(mt - M) : 0.f;
    float lw = lt * w;
#pragma unroll
    for (int off = 32; off > 0; off >>= 1) lw += __shfl_xor(lw, off);
    wsh[t] = w;
    if (t == 0) Lsh = lw;
  }
  __syncthreads();

  const float Linv = 1.f / Lsh;
  float acc = 0.f;
#pragma unroll 8
  for (int i = 0; i < nspl; ++i)
    acc += wsh[i] * ws[POFF + (size_t)(h * NSPL + i) * PSTRIDE + 4 + t];
  ws[CTXOFF + h * HD + t] = acc * Linv;
}

// ---------------- output projection GEMV (R2, proven) ----------------
__global__ __launch_bounds__(256) void o_gemv(
    const float* __restrict__ ow, const float* __restrict__ ws,
    float* __restrict__ out) {
  __shared__ float xs[H];              // 16 KB (ctx)
  const int t = threadIdx.x;
  {
    const float4* xr = (const float4*)(ws + CTXOFF);
    float4* xsv = (float4*)xs;
#pragma unroll
    for (int i = 0; i < 4; ++i) xsv[i * 256 + t] = xr[i * 256 + t];
  }
  __syncthreads();

  const int wave = t >> 6;
  const int lane = t & 63;
  const int row  = blockIdx.x * 4 + wave;

  const float4* wr = (const float4*)(ow + (size_t)row * H);
  float4 a[16];
#pragma unroll
  for (int j = 0; j < 16; ++j) a[j] = wr[j * 64 + lane];

  float sum = 0.f;
#pragma unroll
  for (int j = 0; j < 16; ++j) {
    const float4 b = *(const float4*)&xs[(j * 64 + lane) * 4];
    sum = fmaf(a[j].x, b.x, sum);
    sum = fmaf(a[j].y, b.y, sum);
    sum = fmaf(a[j].z, b.z, sum);
    sum = fmaf(a[j].w, b.w, sum);
  }
#pragma unroll
  for (int off = 32; off > 0; off >>= 1) sum += __shfl_xor(sum, off);
  if (lane == 0) out[row] = sum;
}

extern "C" void kernel_launch(void* const* d_in, const int* in_sizes, int n_in,
                              void* d_out, int out_size, void* d_ws, size_t ws_size,
                              hipStream_t stream) {
  const float* hs   = (const float*)d_in[0];   // hidden_states (1,1,4096)
  const float* kc   = (const float*)d_in[2];   // (1,8,2048,128)
  const float* vc   = (const float*)d_in[3];
  const float* qw   = (const float*)d_in[4];   // (4096,4096)
  const float* kw   = (const float*)d_in[5];   // (1024,4096)
  const float* vw   = (const float*)d_in[6];   // (1024,4096)
  const float* ow   = (const float*)d_in[7];   // (4096,4096)
  const float* cosc = (const float*)d_in[8];   // (1,4096,128)
  const float* sinc = (const float*)d_in[9];
  const int*   cur  = (const int*)d_in[11];    // current_pos scalar
  float* ws  = (float*)d_ws;
  float* out = (float*)d_out;

  // ATTRIBUTION ROUND 2: attn_split and attn_combine launched twice
  // (both idempotent). X = dur - 42.65 = t_attn + t_comb + 2*gap,
  // and t_o = 27.91 - X exactly (using R9's t_qkv + gap = 14.74).
  qkv_gemv<<<1536, 256, 0, stream>>>(hs, qw, kw, vw, ws);
  attn_split<<<dim3(NKV, NSPL), 256, 0, stream>>>(kc, vc, cosc, sinc, cur, ws);
  attn_split<<<dim3(NKV, NSPL), 256, 0, stream>>>(kc, vc, cosc, sinc, cur, ws);
  attn_combine<<<NH, 128, 0, stream>>>(cur, ws);
  attn_combine<<<NH, 128, 0, stream>>>(cur, ws);
  o_gemv<<<1024, 256, 0, stream>>>(ow, ws, out);
}